// Round 5
// baseline (2409.684 us; speedup 1.0000x reference)
//
#include <hip/hip_runtime.h>

#define LOOKBACK 48
#define HORIZON  12
#define TTOT     60
#define INPUT_DIM 8
#define HIDDEN   128
#define GATES    512
#define BATCH    8192
#define TILE_B   32          /* batch rows per block (2 M-tiles of 16) */
#define NTHREADS 512         /* 8 waves; wave s owns hidden units s*16..s*16+15 */
#define NSLICES  8
#define L0_KS    5           /* layer0 K = 160 (8 x + 128 h0 + 24 zero-pad) */
#define L1_KS    8           /* layer1 K = 256 (128 h0 + 128 h1) */
#define FRAGS_PER_KS 8       /* 4 gate-type N-tiles x {hi,lo} */
#define FRAG_SHORTS 512      /* 1KB per fragment */
#define KSTRIDE  (FRAGS_PER_KS * FRAG_SHORTS)            /* 4096 shorts per K-step */
#define SLICE_FRAGS ((L0_KS + L1_KS) * FRAGS_PER_KS)     /* 104 */
#define W_SHORTS (NSLICES * SLICE_FRAGS * FRAG_SHORTS)   /* 425984 shorts = 832KB */

/* A-plane LDS, double-buffered by timestep parity.
   A0 buf = 20 chunks: [0]=x, [1..16]=h0 (chunk 1+(u>>3)), [17..19]=zero pad.
   A1 buf = 16 chunks: h1 (chunk u>>3).
   chunk = [ROWP rows][8 bf16], ROWP=33 (pad breaks 512B quad stride). */
#define ROWP 33
#define CHUNK_SHORTS (ROWP * 8)            /* 264 */
#define A0_BUF (20 * CHUNK_SHORTS)         /* 5280 */
#define A1_BUF (16 * CHUNK_SHORTS)         /* 4224 */
#define A0_SHORTS (2 * A0_BUF)
#define A1_SHORTS (2 * A1_BUF)

typedef __attribute__((ext_vector_type(8))) short short8;
typedef __attribute__((ext_vector_type(4))) float f32x4;

__device__ __forceinline__ unsigned short bf16_rn(float v) {
    unsigned int x = __float_as_uint(v);
    unsigned int r = x + 0x7fffu + ((x >> 16) & 1u);
    return (unsigned short)(r >> 16);
}
__device__ __forceinline__ float bf16_to_f(unsigned short h) {
    return __uint_as_float(((unsigned int)h) << 16);
}
__device__ __forceinline__ float sigm(float x) {
    return 1.0f / (1.0f + __expf(-x));
}
__device__ __forceinline__ float tanh_fast(float x) {
    float ax = fabsf(x);
    float e  = __expf(-2.0f * ax);
    float t  = (1.0f - e) / (1.0f + e);
    return copysignf(t, x);
}

/* Barrier WITHOUT vmcnt drain: LDS ordering only; global conveyor loads stay
   in flight across the barrier. */
#define BARRIER() __asm__ volatile("s_waitcnt lgkmcnt(0)\ns_barrier" ::: "memory")

// ------------- setup: split weights hi/lo bf16, store in MFMA-fragment order -------------
__global__ void setup_kernel(const float* __restrict__ Wih0, const float* __restrict__ Whh0,
                             const float* __restrict__ bi0,  const float* __restrict__ bh0,
                             const float* __restrict__ Wih1, const float* __restrict__ Whh1,
                             const float* __restrict__ bi1,  const float* __restrict__ bh1,
                             unsigned short* __restrict__ wfrag, float* __restrict__ bias) {
    int idx = blockIdx.x * blockDim.x + threadIdx.x;
    if (idx < W_SHORTS) {
        int e = idx & 511, frag = idx >> 9;
        int lane = e >> 3, j = e & 7;
        int p = frag & 1, t = (frag >> 1) & 3;
        int rest = frag >> 3;
        int lks = rest % (L0_KS + L1_KS), s = rest / (L0_KS + L1_KS);
        int l = (lks < L0_KS) ? 0 : 1;
        int ks = l ? (lks - L0_KS) : lks;
        int k = ks * 32 + ((lane >> 4) << 3) + j;
        int uu = s * 16 + (lane & 15);
        int row = t * HIDDEN + uu;
        float v = 0.0f;
        if (l == 0) {
            if (k < INPUT_DIM) v = Wih0[row * INPUT_DIM + k];
            else if (k < INPUT_DIM + HIDDEN) v = Whh0[row * HIDDEN + (k - INPUT_DIM)];
        } else {
            if (k < HIDDEN) v = Wih1[row * HIDDEN + k];
            else v = Whh1[row * HIDDEN + (k - HIDDEN)];
        }
        unsigned short hi = bf16_rn(v);
        wfrag[idx] = (p == 0) ? hi : bf16_rn(v - bf16_to_f(hi));
    } else if (idx < W_SHORTS + 2 * GATES) {
        int g = idx - W_SHORTS;
        bias[g] = (g < GATES) ? (bi0[g] + bh0[g]) : (bi1[g - GATES] + bh1[g - GATES]);
    }
}

// ------------- persistent 2-layer LSTM, MFMA + conveyor + parity double-buffer -------------
__global__ __launch_bounds__(NTHREADS, 2)
void lstm_kernel(const float* __restrict__ input,   // [B,60,8]
                 const unsigned short* __restrict__ wfrag,
                 const float* __restrict__ bias01,  // [1024]
                 const float* __restrict__ W_fc,    // [128]
                 const float* __restrict__ b_fc,
                 float* __restrict__ out) {         // [B,12]
    __shared__ unsigned short A0h[A0_SHORTS], A0l[A0_SHORTS];
    __shared__ unsigned short A1h_[A1_SHORTS], A1l_[A1_SHORTS];
    __shared__ float wfcs[HIDDEN];

    const int tid  = threadIdx.x;
    const int lane = tid & 63;
    const int s    = tid >> 6;
    const int col  = lane & 15;
    const int quad = lane >> 4;
    const int u    = s * 16 + col;
    const int batch0 = blockIdx.x * TILE_B;

    const unsigned short* w0 = wfrag + s * (SLICE_FRAGS * FRAG_SHORTS);
    const unsigned short* w1 = w0 + L0_KS * KSTRIDE;

    for (int i = tid; i < A0_SHORTS; i += NTHREADS) { A0h[i] = 0; A0l[i] = 0; }
    for (int i = tid; i < A1_SHORTS; i += NTHREADS) { A1h_[i] = 0; A1l_[i] = 0; }
    if (tid < HIDDEN) wfcs[tid] = W_fc[tid];
    const float bfc = b_fc[0];

    float bv0[4], bv1[4];
#pragma unroll
    for (int tt = 0; tt < 4; ++tt) {
        bv0[tt] = bias01[tt * HIDDEN + u];
        bv1[tt] = bias01[GATES + tt * HIDDEN + u];
    }

    float c0[2][4] = {}, c1[2][4] = {};

    // x(0) prefetch + stage into buf 0
    float xv = 0.0f;
    if (tid < TILE_B * INPUT_DIM)
        xv = input[(size_t)(batch0 + (tid >> 3)) * (TTOT * INPUT_DIM) + (tid & 7)];
    BARRIER();                               // zero-init visible
    if (tid < TILE_B * INPUT_DIM) {
        int r = tid >> 3, k = tid & 7;
        unsigned short hi = bf16_rn(xv);
        A0h[r * 8 + k] = hi;
        A0l[r * 8 + k] = bf16_rn(xv - bf16_to_f(hi));
    }

    short8 bh[3][4], bl[3][4];               // B conveyor (depth 3)
    short8 ah[2][2], al[2][2];               // A double buffer

#define WPOS(p) ((p) < L0_KS ? (w0 + (p) * KSTRIDE) : (w1 + ((p) - L0_KS) * KSTRIDE))
#define LOADB(p, sl) { const unsigned short* wp_ = WPOS(p) + lane * 8;          \
    _Pragma("unroll") for (int tt = 0; tt < 4; ++tt) {                          \
        bh[sl][tt] = *(const short8*)(wp_ + (tt * 2) * FRAG_SHORTS);            \
        bl[sl][tt] = *(const short8*)(wp_ + (tt * 2 + 1) * FRAG_SHORTS); } }
#define LOADA(Hh, Hl, off, chunk, buf) {                                        \
    int base_ = (off) + ((chunk) * ROWP + col) * 8;                             \
    ah[buf][0] = *(const short8*)(Hh + base_);                                  \
    ah[buf][1] = *(const short8*)(Hh + base_ + 16 * 8);                         \
    al[buf][0] = *(const short8*)(Hl + base_);                                  \
    al[buf][1] = *(const short8*)(Hl + base_ + 16 * 8); }
/* interleave the 3 split-products across the 8 acc chains: no back-to-back
   same-acc MFMAs anywhere */
#define COMP(ACC, ab, sl)                                                       \
    _Pragma("unroll") for (int tt = 0; tt < 4; ++tt)                            \
    _Pragma("unroll") for (int mt = 0; mt < 2; ++mt)                            \
        ACC[mt][tt] = __builtin_amdgcn_mfma_f32_16x16x32_bf16(                  \
            ah[ab][mt], bh[sl][tt], ACC[mt][tt], 0, 0, 0);                      \
    _Pragma("unroll") for (int tt = 0; tt < 4; ++tt)                            \
    _Pragma("unroll") for (int mt = 0; mt < 2; ++mt)                            \
        ACC[mt][tt] = __builtin_amdgcn_mfma_f32_16x16x32_bf16(                  \
            al[ab][mt], bh[sl][tt], ACC[mt][tt], 0, 0, 0);                      \
    _Pragma("unroll") for (int tt = 0; tt < 4; ++tt)                            \
    _Pragma("unroll") for (int mt = 0; mt < 2; ++mt)                            \
        ACC[mt][tt] = __builtin_amdgcn_mfma_f32_16x16x32_bf16(                  \
            ah[ab][mt], bl[sl][tt], ACC[mt][tt], 0, 0, 0);

    LOADB(0, 0) LOADB(1, 1) LOADB(2, 2)      // prime conveyor
    BARRIER();                               // x(0) staged & visible

#pragma unroll 1
    for (int t = 0; t < TTOT; ++t) {
        const int rb = t & 1, wb = rb ^ 1;
        const int a0r = A0_BUF * rb, a0w = A0_BUF * wb;
        const int a1r = A1_BUF * rb, a1w = A1_BUF * wb;

        // prefetch x(t+1) into registers (staged later this phase)
        if (tid < TILE_B * INPUT_DIM && t + 1 < TTOT)
            xv = input[(size_t)(batch0 + (tid >> 3)) * (TTOT * INPUT_DIM)
                       + (t + 1) * INPUT_DIM + (tid & 7)];

        // ======== P1: GEMM0 (reads buf rb) + cell0 + x-stage (writes buf wb) ========
        f32x4 acc[2][4];
#pragma unroll
        for (int tt = 0; tt < 4; ++tt) {
            f32x4 b = {bv0[tt], bv0[tt], bv0[tt], bv0[tt]};
            acc[0][tt] = b; acc[1][tt] = b;
        }
        LOADA(A0h, A0l, a0r, quad, 0)
        LOADA(A0h, A0l, a0r, 4 + quad, 1)  COMP(acc, 0, 0) LOADB(3, 0)
        LOADA(A0h, A0l, a0r, 8 + quad, 0)  COMP(acc, 1, 1) LOADB(4, 1)
        LOADA(A0h, A0l, a0r, 12 + quad, 1) COMP(acc, 0, 2) LOADB(5, 2)
        LOADA(A0h, A0l, a0r, 16 + quad, 0) COMP(acc, 1, 0) LOADB(6, 0)
                                           COMP(acc, 0, 1) LOADB(7, 1)

        // cell 0 -> h0(t) into buf wb chunks 1..16
#pragma unroll
        for (int mt = 0; mt < 2; ++mt) {
#pragma unroll
            for (int r = 0; r < 4; ++r) {
                float ig = sigm(acc[mt][0][r]);
                float fg = sigm(acc[mt][1][r]);
                float gg = tanh_fast(acc[mt][2][r]);
                float og = sigm(acc[mt][3][r]);
                float cn = fg * c0[mt][r] + ig * gg;
                c0[mt][r] = cn;
                float h = og * tanh_fast(cn);
                unsigned short hi = bf16_rn(h);
                int row = mt * 16 + quad * 4 + r;
                int i0 = a0w + ((1 + (u >> 3)) * ROWP + row) * 8 + (u & 7);
                A0h[i0] = hi;
                A0l[i0] = bf16_rn(h - bf16_to_f(hi));
            }
        }
        // stage x(t+1) into buf wb chunk 0 (BG slot filled by fc for decode)
        if (tid < TILE_B * INPUT_DIM && t + 1 < TTOT) {
            int r = tid >> 3, k = tid & 7;
            if (!(t + 1 > LOOKBACK && k == 0)) {
                unsigned short hi = bf16_rn(xv);
                A0h[a0w + r * 8 + k] = hi;
                A0l[a0w + r * 8 + k] = bf16_rn(xv - bf16_to_f(hi));
            }
        }
        BARRIER();                           // Ba: h0(t) + x(t+1) visible

        // ======== P2: GEMM1 (reads h0 buf wb, h1 buf rb) + cell1 (writes buf wb) ========
#pragma unroll
        for (int tt = 0; tt < 4; ++tt) {
            f32x4 b = {bv1[tt], bv1[tt], bv1[tt], bv1[tt]};
            acc[0][tt] = b; acc[1][tt] = b;
        }
        LOADA(A0h, A0l, a0w, 1 + quad, 0)
        LOADA(A0h, A0l, a0w, 5 + quad, 1)    COMP(acc, 0, 2) LOADB(8, 2)
        LOADA(A0h, A0l, a0w, 9 + quad, 0)    COMP(acc, 1, 0) LOADB(9, 0)
        LOADA(A0h, A0l, a0w, 13 + quad, 1)   COMP(acc, 0, 1) LOADB(10, 1)
        LOADA(A1h_, A1l_, a1r, quad, 0)      COMP(acc, 1, 2) LOADB(11, 2)
        LOADA(A1h_, A1l_, a1r, 4 + quad, 1)  COMP(acc, 0, 0) LOADB(12, 0)
        LOADA(A1h_, A1l_, a1r, 8 + quad, 0)  COMP(acc, 1, 1) LOADB(1, 1)   // next t
        LOADA(A1h_, A1l_, a1r, 12 + quad, 1) COMP(acc, 0, 2) LOADB(2, 2)   // next t
                                             COMP(acc, 1, 0) LOADB(0, 0)   // next t

        // cell 1 -> h1(t) into buf wb
#pragma unroll
        for (int mt = 0; mt < 2; ++mt) {
#pragma unroll
            for (int r = 0; r < 4; ++r) {
                float ig = sigm(acc[mt][0][r]);
                float fg = sigm(acc[mt][1][r]);
                float gg = tanh_fast(acc[mt][2][r]);
                float og = sigm(acc[mt][3][r]);
                float cn = fg * c1[mt][r] + ig * gg;
                c1[mt][r] = cn;
                float h = og * tanh_fast(cn);
                unsigned short hi = bf16_rn(h);
                int row = mt * 16 + quad * 4 + r;
                int i1 = a1w + ((u >> 3) * ROWP + row) * 8 + (u & 7);
                A1h_[i1] = hi;
                A1l_[i1] = bf16_rn(h - bf16_to_f(hi));
            }
        }

        // ======== decode head (12 of 60 steps) ========
        if (t >= LOOKBACK) {
            BARRIER();                       // h1(t) visible
            int r = tid >> 4, sub = tid & 15;
            float p = 0.0f;
#pragma unroll
            for (int i = 0; i < HIDDEN / 16; ++i) {
                int uu = sub + i * 16;
                int idx = a1w + ((uu >> 3) * ROWP + r) * 8 + (uu & 7);
                p += (bf16_to_f(A1h_[idx]) + bf16_to_f(A1l_[idx])) * wfcs[uu];
            }
#pragma unroll
            for (int off = 8; off; off >>= 1) p += __shfl_down(p, off, 16);
            if (sub == 0) {
                float pr = p + bfc;
                out[(size_t)(batch0 + r) * HORIZON + (t - LOOKBACK)] = pr;
                if (t + 1 < TTOT) {          // BG feedback -> x(t+1) slot k=0 (buf wb)
                    unsigned short hi = bf16_rn(pr);
                    A0h[a0w + r * 8] = hi;
                    A0l[a0w + r * 8] = bf16_rn(pr - bf16_to_f(hi));
                }
            }
            BARRIER();                       // BG slot visible before next P1
        }
        // encoder: NO barrier here — waves free-flow into P1(t+1)
    }
#undef WPOS
#undef LOADB
#undef LOADA
#undef COMP
}

extern "C" void kernel_launch(void* const* d_in, const int* in_sizes, int n_in,
                              void* d_out, int out_size, void* d_ws, size_t ws_size,
                              hipStream_t stream) {
    const float* input = (const float*)d_in[0];
    const float* Wih0  = (const float*)d_in[1];
    const float* Whh0  = (const float*)d_in[2];
    const float* bi0   = (const float*)d_in[3];
    const float* bh0   = (const float*)d_in[4];
    const float* Wih1  = (const float*)d_in[5];
    const float* Whh1  = (const float*)d_in[6];
    const float* bi1   = (const float*)d_in[7];
    const float* bh1   = (const float*)d_in[8];
    const float* W_fc  = (const float*)d_in[9];
    const float* b_fc  = (const float*)d_in[10];

    unsigned short* wfrag = (unsigned short*)d_ws;
    float* bias = (float*)((char*)d_ws + (size_t)W_SHORTS * sizeof(unsigned short));

    int total = W_SHORTS + 2 * GATES;
    setup_kernel<<<(total + 255) / 256, 256, 0, stream>>>(
        Wih0, Whh0, bi0, bh0, Wih1, Whh1, bi1, bh1, wfrag, bias);

    lstm_kernel<<<BATCH / TILE_B, NTHREADS, 0, stream>>>(
        input, wfrag, bias, W_fc, b_fc, (float*)d_out);
}